// Round 3
// baseline (1923.796 us; speedup 1.0000x reference)
//
#include <hip/hip_runtime.h>
#include <math.h>

// FISTA, phase-split 4x, XCD-colocated, L3-atomic exchange — R20.
// R19 post-mortem: launch_bounds(512,2) pinned VGPR at the 128 cap (spill /
// sched squeeze), and the 8-wave rebalance didn't pay because the DPP
// butterfly reduction (324 instr/pass = 33% of stage-1 issue) dominates, not
// row imbalance. R20:
//  - __launch_bounds__(512) only: 256-VGPR budget, no spill; 72.6 KB LDS
//    also forces 1 block/CU (kills 2-block packing pathology).
//  - Reduction: per-wave LDS transpose (stride-66 rows, <=2-way banks, free):
//    27 ds_write_b32 + (lanes<27) 32 ds_read_b64 + 4-acc sums + ONE coalesced
//    27-lane atomic store. ~100 instr vs 324+27 serial stores.
//  - Pre-pass phase DELETED: stage-2 threads load their 12 partials
//    (3 channels x 4 g) directly from L3 (relaxed agent atomic loads).
//    3 __syncthreads/iter instead of 4; LA/LXS/LWCT LDS regions gone.
//  - y_last, x-slice, Wct, biases in REGISTERS (y_last is private to its
//    owning stage-2 thread; others are iteration-invariant).
//  - Barrier itself: R17-proven centralized form (sync; tid0 relaxed
//    fetch_add + relaxed spin, target 4*(iter+1); sync).
// WAR audit: stage2(k) reads buf k&1; rewrite of buf k&1 is stage1(k+2),
// gated on count>=4(k+2) <= every block's add(k+1) <= its stage2(k) done.
//
// Phase decomposition (proven R2-R19): a[cell,co] = sum_{d(5x5),ci,p}
// y[cell+d,ci,p] W[d,ci,p,co]; block g sums its 16 phases -> partial a.
// Wave = output row; lane = (q=ci quadrant, p_local); q=3 lanes carry zero
// weights (y reads duplicate q=2: same-address broadcast, free).

#define ITERS 200
#define THREADS 512
// d_ws float offsets
#define WGOFF 0          // 19200: [g][t*3+co][lane], q=3 lanes zeroed
#define WCTOFF 19200     // 576: [c][ci][p]
#define APOFF 19776      // 2 * 64 * 4 * 243 = 124416 (double-buffered)
#define CNTOFF 144192    // int offsets: 64 images x 64-int padding
// LDS float offsets
#define LY 0             // y: 3888 = 243 idx3 x 16 p_local
#define LT 3888          // transpose scratch: 8 waves x 27 rows x stride 66
#define TSTRIDE 66       // even (8B-aligned b64 reads), 66%32=2 -> <=2-way banks
#define TWAVE (27 * TSTRIDE)   // 1782
#define SMEMF (3888 + 8 * TWAVE)  // 18144 floats = 72,576 B

// WG[((g*75 + t*3 + co))*64 + lane] = w_conv[8*th+ph][8*tw+pw][ci=q][co]
//   with lane=(q,pl), p = g*16+pl; q==3 -> 0 (dead quadrant).
// WCT2[c*192 + ci*64 + p] = (rh<5 && rw<5) ? w_ct[4-rh][4-rw][ci][c] : 0,
//   p = rh*8+rw.
__global__ void k0_init(const float* __restrict__ w_conv,
                        const float* __restrict__ w_ct,
                        float* __restrict__ ws) {
  const int i = blockIdx.x * 256 + threadIdx.x;
  if (i < 19200) {
    const int lane = i & 63;
    const int rest = i >> 6;          // g*75 + t*3 + co
    const int g = rest / 75;
    const int tc = rest - 75 * g;
    const int t = tc / 3;
    const int co = tc - 3 * t;
    const int th = t / 5;
    const int tw = t - 5 * th;
    const int q = lane >> 4;
    const int pl = lane & 15;
    float v = 0.f;
    if (q < 3) {
      const int p = g * 16 + pl;
      const int ph = p >> 3;
      const int pw = p & 7;
      v = w_conv[(((8 * th + ph) * 40 + (8 * tw + pw)) * 3 + q) * 3 + co];
    }
    ws[WGOFF + i] = v;
  }
  if (i < 576) {
    const int p = i & 63;
    const int ci = (i >> 6) % 3;
    const int c = i / 192;
    const int rh = p >> 3;
    const int rw = p & 7;
    float v = 0.f;
    if (rh < 5 && rw < 5) v = w_ct[(((4 - rh) * 5 + (4 - rw)) * 3 + ci) * 3 + c];
    ws[WCTOFF + i] = v;
  }
  if (i < 4096) ((int*)ws)[CNTOFF + i] = 0;
}

__global__ __launch_bounds__(THREADS) void fista_split(
    float* __restrict__ ws,
    const float* __restrict__ x, const float* __restrict__ lam,
    const float* __restrict__ b_conv, const float* __restrict__ b_ct,
    float* __restrict__ out) {
  __shared__ __align__(16) float smem[SMEMF];
  const int tid = threadIdx.x;
  const int blk = blockIdx.x;
  const int n = blk & 63;         // image  (XCD colocation: n, n+64, n+128,
  const int g = blk >> 6;         //  n+192 share blk%8)
  const int lane = tid & 63;
  const int wid = tid >> 6;       // wave index, 8 waves
  const int q = lane >> 4;        // ci quadrant (3 = dead)
  const int pl = lane & 15;
  const int ylane = ((q < 3) ? q : 2) * 16 + pl;  // q=3 dupes q=2: broadcast
  // Waves 1-7 -> rows {2,4,6,1,3,5,7}; wave 0 -> rows 0 AND 8 (both 3-tap).
  const int row0 = (wid & 3) * 2 + (wid >> 2);
  const int npass = (wid == 0) ? 2 : 1;

  int* __restrict__ cnt = (int*)ws + CNTOFF + n * 64;
  const float lam_n = lam[n];

  // ---- conv weights -> 75 VGPRs (iteration-invariant) ----
  float wreg[75];
#pragma unroll
  for (int i = 0; i < 75; ++i) wreg[i] = ws[WGOFF + g * 4800 + i * 64 + lane];

  // ---- stage-2 per-thread constants: thread t<486 owns y elements
  // e = 8t .. 8t+7  (idx3 = t>>1, pl-half = t&1); y_last lives in regs ----
  const int idx3 = tid >> 1;
  const int cell = idx3 / 3;
  const int c = idx3 - 3 * cell;
  const int cb = 3 * cell;
  const int pbase = g * 16 + (tid & 1) * 8;
  float wct[3][8];
  float yl[8];
#pragma unroll
  for (int j = 0; j < 8; ++j) yl[j] = 0.f;
  float xr0 = 0.f, xr1 = 0.f, xr2 = 0.f;
  float bc0 = 0.f, bc1 = 0.f, bc2 = 0.f, bctc = 0.f;
  if (tid < 486) {
#pragma unroll
    for (int ci = 0; ci < 3; ++ci)
#pragma unroll
      for (int j = 0; j < 8; ++j)
        wct[ci][j] = ws[WCTOFF + c * 192 + ci * 64 + pbase + j];
    bctc = b_ct[c];
    bc0 = b_conv[0]; bc1 = b_conv[1]; bc2 = b_conv[2];
    xr0 = x[n * 243 + cb + 0];
    xr1 = x[n * 243 + cb + 1];
    xr2 = x[n * 243 + cb + 2];
  }

  // ---- stage LDS: zero y ----
  for (int i = tid; i < 3888; i += THREADS) smem[LY + i] = 0.f;
  __syncthreads();

  float t = 1.0f;
#pragma unroll 1
  for (int iter = 0; iter < ITERS; ++iter) {
    // ===== stage 1: partial a over this block's 16 phases =====
#pragma unroll 1
    for (int pass = 0; pass < npass; ++pass) {
      const int oh = pass ? 8 : row0;
      float acc[27];               // [ow*3 + co]
#pragma unroll
      for (int k = 0; k < 27; ++k) acc[k] = 0.f;

#pragma unroll
      for (int th = 0; th < 5; ++th) {
        const int r = oh + th - 2;          // input row
        if (r >= 0 && r <= 8) {
          float rv[13];                     // y col (k-2), zero-padded
          rv[0] = 0.f; rv[1] = 0.f; rv[11] = 0.f; rv[12] = 0.f;
#pragma unroll
          for (int wc = 0; wc < 9; ++wc)
            rv[wc + 2] = smem[LY + r * 432 + wc * 48 + ylane];

#pragma unroll
          for (int tw = 0; tw < 5; ++tw) {
            const int tb = (th * 5 + tw) * 3;
            const float w0 = wreg[tb + 0];
            const float w1 = wreg[tb + 1];
            const float w2 = wreg[tb + 2];
#pragma unroll
            for (int ow = 0; ow < 9; ++ow) {
              const float y = rv[ow + tw];
              acc[ow * 3 + 0] += y * w0;
              acc[ow * 3 + 1] += y * w1;
              acc[ow * 3 + 2] += y * w2;
            }
          }
        }
      }

      // ---- per-wave LDS transpose reduce: lane k<27 sums column k, then
      // ONE coalesced 27-lane atomic store. DS ops are in-order per wave;
      // the waitcnt guards wave0's pass-2 WAR on its scratch region. ----
      float* Tw = &smem[LT + wid * TWAVE];
      asm volatile("s_waitcnt lgkmcnt(0)" ::: "memory");
#pragma unroll
      for (int k = 0; k < 27; ++k) Tw[k * TSTRIDE + lane] = acc[k];
      if (lane < 27) {
        const float2* Tr = (const float2*)&Tw[lane * TSTRIDE];
        float s0 = 0.f, s1 = 0.f, s2 = 0.f, s3 = 0.f;
#pragma unroll
        for (int j = 0; j < 16; ++j) {
          const float2 u = Tr[2 * j];
          const float2 v = Tr[2 * j + 1];
          s0 += u.x; s1 += u.y; s2 += v.x; s3 += v.y;
        }
        const float s = (s0 + s2) + (s1 + s3);
        float* ap = ws + APOFF + ((((iter & 1) * 64 + n) * 4 + g) * 243)
                    + oh * 27 + lane;
        __hip_atomic_store(ap, s, __ATOMIC_RELAXED, __HIP_MEMORY_SCOPE_AGENT);
      }
    }

    // ===== centralized barrier (R17-proven): one spinner, rest at s_barrier ==
    __syncthreads();               // drains vmcnt: Ap stores acked at L3
    if (tid == 0) {
      __hip_atomic_fetch_add(cnt, 1, __ATOMIC_RELAXED, __HIP_MEMORY_SCOPE_AGENT);
      const int target = 4 * (iter + 1);
      while (__hip_atomic_load(cnt, __ATOMIC_RELAXED, __HIP_MEMORY_SCOPE_AGENT)
             < target)
        __builtin_amdgcn_s_sleep(1);
    }
    __syncthreads();

    const float tn = (1.0f + sqrtf(1.0f + 4.0f * t * t)) * 0.5f;
    const float beta = (t - 1.0f) / tn;    // beta_0 = 0
    t = tn;

    // ===== stage 2: 8 consecutive elements per thread; partials direct
    // from L3 (12 relaxed atomic loads, latency-parallel) =====
    const bool lastit = (iter == ITERS - 1);
    if (tid < 486) {
      const float* apb = ws + APOFF + ((iter & 1) * 64 + n) * 972;
      float pv[3][4];
#pragma unroll
      for (int c2 = 0; c2 < 3; ++c2)
#pragma unroll
        for (int g2 = 0; g2 < 4; ++g2)
          pv[c2][g2] = __hip_atomic_load(apb + g2 * 243 + cb + c2,
                                         __ATOMIC_RELAXED,
                                         __HIP_MEMORY_SCOPE_AGENT);
      const float a0 = (((pv[0][0] + pv[0][1]) + pv[0][2]) + pv[0][3]) + bc0;
      const float a1 = (((pv[1][0] + pv[1][1]) + pv[1][2]) + pv[1][3]) + bc1;
      const float a2 = (((pv[2][0] + pv[2][1]) + pv[2][2]) + pv[2][3]) + bc2;
      const float r0 = xr0 - a0;
      const float r1 = xr1 - a1;
      const float r2 = xr2 - a2;

      float4* lyv = (float4*)&smem[LY];
      const float4 y0 = lyv[2 * tid];
      const float4 y1 = lyv[2 * tid + 1];
      const float yv[8] = {y0.x, y0.y, y0.z, y0.w, y1.x, y1.y, y1.z, y1.w};
      float yn[8];
#pragma unroll
      for (int j = 0; j < 8; ++j) {
        const float re = bctc + r0 * wct[0][j] + r1 * wct[1][j] + r2 * wct[2][j];
        const float wvv = yv[j] - re;
        yn[j] = fmaxf(wvv - lam_n, 0.f) - fmaxf(-wvv - lam_n, 0.f);
      }

      if (!lastit) {
        float4 m0, m1;
        m0.x = yn[0] + beta * (yn[0] - yl[0]);
        m0.y = yn[1] + beta * (yn[1] - yl[1]);
        m0.z = yn[2] + beta * (yn[2] - yl[2]);
        m0.w = yn[3] + beta * (yn[3] - yl[3]);
        m1.x = yn[4] + beta * (yn[4] - yl[4]);
        m1.y = yn[5] + beta * (yn[5] - yl[5]);
        m1.z = yn[6] + beta * (yn[6] - yl[6]);
        m1.w = yn[7] + beta * (yn[7] - yl[7]);
#pragma unroll
        for (int j = 0; j < 8; ++j) yl[j] = yn[j];
        lyv[2 * tid] = m0; lyv[2 * tid + 1] = m1;
      } else {
        const int part = pbase >> 3;       // p>>3 constant over j
        const int qh = cell / 9;
        const int qw = cell - 9 * qh;
        const int ih = 8 * qh + part;
        float* op = out + ((n * 72 + ih) * 72 + 8 * qw) * 3 + c;
#pragma unroll
        for (int j = 0; j < 8; ++j) op[3 * j] = yn[j];
      }
    }
    __syncthreads();
  }
}

extern "C" void kernel_launch(void* const* d_in, const int* in_sizes, int n_in,
                              void* d_out, int out_size, void* d_ws, size_t ws_size,
                              hipStream_t stream) {
  const float* x      = (const float*)d_in[0];
  const float* lam    = (const float*)d_in[1];
  const float* w_conv = (const float*)d_in[2];
  const float* b_conv = (const float*)d_in[3];
  const float* w_ct   = (const float*)d_in[4];
  const float* b_ct   = (const float*)d_in[5];
  float* out = (float*)d_out;
  float* ws  = (float*)d_ws;  // needs ~593 KB (unchanged)

  hipLaunchKernelGGL(k0_init, dim3(80), dim3(256), 0, stream, w_conv, w_ct, ws);
  hipLaunchKernelGGL(fista_split, dim3(256), dim3(THREADS), 0, stream,
                     ws, x, lam, b_conv, b_ct, out);
}